// Round 11
// baseline (132.228 us; speedup 1.0000x reference)
//
#include <hip/hip_runtime.h>
#include <math.h>

// MAM "FullyConnected": C[n,m] = max_k(x[n,k]*w[m,k]) + min_k(...) + bias[m]
// plus argmax/argmin (first occurrence). N=1024, M=512, K=512, f32.
// d_out (read back as f32): C | argmax | argmin, each N*M.
//
// Round 11: R9's proven 2x2 inner loop (VGPR~60), but 4 blocks/CU for
// pipe overlap: BM 32->16 (25.3KB LDS/block), 512-thr blocks, k-split x4
// (quarter = 2 waves), 1024 blocks -> 24-32 waves/CU. LDS pipe (20.5us
// demand) becomes saturable; barrier drains hide under sibling blocks.

constexpr int NTOT = 1024;
constexpr int MTOT = 512;
constexpr int KTOT = 512;
constexpr int BN = 32;
constexpr int BM = 16;
constexpr int BK = 128;
constexpr int G  = 16;        // tournament group size
constexpr int LDSP = 132;     // rows 16B-aligned; broadcast row-reads conflict-free

__device__ __forceinline__ float max3f(float a, float b, float c) {
  float d; asm("v_max3_f32 %0, %1, %2, %3" : "=v"(d) : "v"(a), "v"(b), "v"(c)); return d;
}
__device__ __forceinline__ float min3f(float a, float b, float c) {
  float d; asm("v_min3_f32 %0, %1, %2, %3" : "=v"(d) : "v"(a), "v"(b), "v"(c)); return d;
}
__device__ __forceinline__ float fmul0(float a, float b) {  // a*b on the 2-cy FMA pipe
  float d; asm("v_fma_f32 %0, %1, %2, 0" : "=v"(d) : "v"(a), "v"(b)); return d;
}
__device__ __forceinline__ float4 f4mul(float4 a, float4 b) {
  return make_float4(fmul0(a.x, b.x), fmul0(a.y, b.y), fmul0(a.z, b.z), fmul0(a.w, b.w));
}

__device__ __forceinline__ void tree16(const float4& q0, const float4& q1,
                                       const float4& q2, const float4& q3,
                                       float& M, float& m) {
  M = fmaxf(max3f(max3f(q0.x, q0.y, q0.z), max3f(q0.w, q1.x, q1.y),
                  max3f(q1.z, q1.w, q2.x)),
            max3f(max3f(q2.y, q2.z, q2.w), q3.x, max3f(q3.y, q3.z, q3.w)));
  m = fminf(min3f(min3f(q0.x, q0.y, q0.z), min3f(q0.w, q1.x, q1.y),
                  min3f(q1.z, q1.w, q2.x)),
            min3f(min3f(q2.y, q2.z, q2.w), q3.x, min3f(q3.y, q3.z, q3.w)));
}

// value tree over one 16-k group for one cell + running group update.
// strict > / < : first group attaining the extremum wins (first occurrence).
#define CELL(S, A0, A1, A2, A3, B0, B1, B2, B3)                              \
  {                                                                          \
    const float4 q0 = f4mul(A0, B0), q1 = f4mul(A1, B1);                     \
    const float4 q2 = f4mul(A2, B2), q3 = f4mul(A3, B3);                     \
    float M, m;                                                              \
    tree16(q0, q1, q2, q3, M, m);                                            \
    const bool u = M > vmax##S;                                              \
    vmax##S = u ? M : vmax##S;  gx##S = u ? gk : gx##S;                      \
    const bool v = m < vmin##S;                                              \
    vmin##S = v ? m : vmin##S;  gn##S = v ? gk : gn##S;                      \
  }

// first k in [base, base+16) with x[k]*w[k] == tgt (descending selects ->
// first occurrence wins; +-0 compare-equal so fma(+0) targets match mul).
__device__ __forceinline__ int find_first_eq(const float* __restrict__ xr,
                                             const float* __restrict__ wr,
                                             float tgt, int base) {
  const float4 a0 = *(const float4*)(xr + 0),  a1 = *(const float4*)(xr + 4);
  const float4 a2 = *(const float4*)(xr + 8),  a3 = *(const float4*)(xr + 12);
  const float4 b0 = *(const float4*)(wr + 0),  b1 = *(const float4*)(wr + 4);
  const float4 b2 = *(const float4*)(wr + 8),  b3 = *(const float4*)(wr + 12);
  int idx = base;
  idx = (a3.w * b3.w == tgt) ? base + 15 : idx;
  idx = (a3.z * b3.z == tgt) ? base + 14 : idx;
  idx = (a3.y * b3.y == tgt) ? base + 13 : idx;
  idx = (a3.x * b3.x == tgt) ? base + 12 : idx;
  idx = (a2.w * b2.w == tgt) ? base + 11 : idx;
  idx = (a2.z * b2.z == tgt) ? base + 10 : idx;
  idx = (a2.y * b2.y == tgt) ? base +  9 : idx;
  idx = (a2.x * b2.x == tgt) ? base +  8 : idx;
  idx = (a1.w * b1.w == tgt) ? base +  7 : idx;
  idx = (a1.z * b1.z == tgt) ? base +  6 : idx;
  idx = (a1.y * b1.y == tgt) ? base +  5 : idx;
  idx = (a1.x * b1.x == tgt) ? base +  4 : idx;
  idx = (a0.w * b0.w == tgt) ? base +  3 : idx;
  idx = (a0.z * b0.z == tgt) ? base +  2 : idx;
  idx = (a0.y * b0.y == tgt) ? base +  1 : idx;
  idx = (a0.x * b0.x == tgt) ? base +  0 : idx;
  return idx;
}

__global__ __launch_bounds__(512, 6) void mam_kernel(
    const float* __restrict__ X,   // [NTOT][KTOT]
    const float* __restrict__ W,   // [MTOT][KTOT]
    const float* __restrict__ B,   // [MTOT]
    float* __restrict__ out)
{
  __shared__ float sx[BN][LDSP];   // 16.9 KB
  __shared__ float sw[BM][LDSP];   // 8.45 KB

  const int th      = threadIdx.x;     // 0..511
  const int quarter = th >> 7;         // 0..3 (2 waves each), k-split quarter
  const int t       = th & 127;
  const int n0 = blockIdx.y * BN;
  const int m0 = blockIdx.x * BM;

  const int tn = t >> 3;               // 0..15
  const int tm = t & 7;                // 0..7
  const int r0 = tn, r1 = tn + 16;     // 2 output rows (of 32)
  const int c0 = tm, c1 = tm + 8;      // 2 output cols (of 16)
  const int kbase = quarter * 32;      // this quarter's kk range within BK

  float vmax00 = -INFINITY, vmax01 = -INFINITY, vmax10 = -INFINITY, vmax11 = -INFINITY;
  float vmin00 =  INFINITY, vmin01 =  INFINITY, vmin10 =  INFINITY, vmin11 =  INFINITY;
  int   gx00 = 0, gx01 = 0, gx10 = 0, gx11 = 0;
  int   gn00 = 0, gn01 = 0, gn10 = 0, gn11 = 0;

  #pragma unroll 1
  for (int kc = 0; kc < KTOT; kc += BK) {
    __syncthreads();  // protect LDS from previous iteration's readers
    // stage x[32][128] (1024 f4) + w[16][128] (512 f4): 512 threads -> 3 each
    #pragma unroll
    for (int j = 0; j < 3; ++j) {
      const int id = th + 512 * j;     // 0..1535 (j<2 -> sx, j==2 -> sw)
      if (id < 1024) {
        const int r = id >> 5, f = id & 31;
        *reinterpret_cast<float4*>(&sx[r][f * 4]) =
            *reinterpret_cast<const float4*>(&X[(n0 + r) * KTOT + kc + f * 4]);
      } else {
        const int r = (id - 1024) >> 5, f = id & 31;
        *reinterpret_cast<float4*>(&sw[r][f * 4]) =
            *reinterpret_cast<const float4*>(&W[(m0 + r) * KTOT + kc + f * 4]);
      }
    }
    __syncthreads();

    #pragma unroll
    for (int g = 0; g < 2; ++g) {      // this quarter's 2 groups of 16 k
      const int off = kbase + g * G;   // wave-uniform
      const int gk  = kc + off;
      const float4* xap = reinterpret_cast<const float4*>(&sx[r0][off]);
      const float4* xbp = reinterpret_cast<const float4*>(&sx[r1][off]);
      const float4* wap = reinterpret_cast<const float4*>(&sw[c0][off]);
      const float4* wbp = reinterpret_cast<const float4*>(&sw[c1][off]);
      const float4 xa0 = xap[0], xa1 = xap[1], xa2 = xap[2], xa3 = xap[3];
      const float4 xb0 = xbp[0], xb1 = xbp[1], xb2 = xbp[2], xb3 = xbp[3];
      const float4 wa0 = wap[0], wa1 = wap[1], wa2 = wap[2], wa3 = wap[3];
      const float4 wb0 = wbp[0], wb1 = wbp[1], wb2 = wbp[2], wb3 = wbp[3];

      CELL(00, xa0, xa1, xa2, xa3, wa0, wa1, wa2, wa3)
      CELL(01, xa0, xa1, xa2, xa3, wb0, wb1, wb2, wb3)
      CELL(10, xb0, xb1, xb2, xb3, wa0, wa1, wa2, wa3)
      CELL(11, xb0, xb1, xb2, xb3, wb0, wb1, wb2, wb3)
    }
  }

  // ---- cross-quarter merge through LDS (ties -> min group id) ----
  // 512 cells (32 rows x 16 cols) * float4 = 8 KB per partial buffer.
  __syncthreads();
  float* combA = &sx[0][0];
  float* combB = &sw[0][0];

#define WRITE_PART(comb)                                                     \
  {                                                                          \
    float* c_ = (comb);                                                      \
    *reinterpret_cast<float4*>(&c_[(r0 * 16 + c0) * 4]) =                    \
        make_float4(vmax00, __int_as_float(gx00), vmin00, __int_as_float(gn00)); \
    *reinterpret_cast<float4*>(&c_[(r0 * 16 + c1) * 4]) =                    \
        make_float4(vmax01, __int_as_float(gx01), vmin01, __int_as_float(gn01)); \
    *reinterpret_cast<float4*>(&c_[(r1 * 16 + c0) * 4]) =                    \
        make_float4(vmax10, __int_as_float(gx10), vmin10, __int_as_float(gn10)); \
    *reinterpret_cast<float4*>(&c_[(r1 * 16 + c1) * 4]) =                    \
        make_float4(vmax11, __int_as_float(gx11), vmin11, __int_as_float(gn11)); \
  }

#define MERGE_ONE(S, RR, CC, comb)                                           \
  {                                                                          \
    const float4 v_ = *reinterpret_cast<const float4*>(&(comb)[((RR) * 16 + (CC)) * 4]); \
    const float pmx = v_.x;  const int pgx = __float_as_int(v_.y);           \
    const float pmn = v_.z;  const int pgn = __float_as_int(v_.w);           \
    if (pmx > vmax##S) { vmax##S = pmx; gx##S = pgx; }                       \
    else if (pmx == vmax##S && pgx < gx##S) { gx##S = pgx; }                 \
    if (pmn < vmin##S) { vmin##S = pmn; gn##S = pgn; }                       \
    else if (pmn == vmin##S && pgn < gn##S) { gn##S = pgn; }                 \
  }

#define MERGE_PART(comb)                                                     \
  {                                                                          \
    MERGE_ONE(00, r0, c0, comb)                                              \
    MERGE_ONE(01, r0, c1, comb)                                              \
    MERGE_ONE(10, r1, c0, comb)                                              \
    MERGE_ONE(11, r1, c1, comb)                                              \
  }

  if (quarter == 1) WRITE_PART(combA);
  if (quarter == 3) WRITE_PART(combB);
  __syncthreads();
  if (quarter == 0) MERGE_PART(combA);
  if (quarter == 2) MERGE_PART(combB);
  __syncthreads();
  if (quarter == 2) WRITE_PART(combA);
  __syncthreads();
  if (quarter == 0) { MERGE_PART(combA); WRITE_PART(combA); }
  __syncthreads();

  // ---- distributed output + windowed index recovery: 1 cell per thread ----
  {
    const int cell = th;                      // 0..511 = 32 rows x 16 cols
    const float4 v = *reinterpret_cast<const float4*>(&combA[cell * 4]);
    const float vmx = v.x;  const int gxc = __float_as_int(v.y);
    const float vmn = v.z;  const int gnc = __float_as_int(v.w);
    const int row = cell >> 4, col = cell & 15;
    const int n = n0 + row, m = m0 + col;
    const float* xr = &X[n * KTOT];
    const float* wr = &W[m * KTOT];
    const int imax = find_first_eq(xr + gxc, wr + gxc, vmx, gxc);
    const int imin = find_first_eq(xr + gnc, wr + gnc, vmn, gnc);

    float* Cout = out;
    float* AM   = out + NTOT * MTOT;
    float* AN   = AM + NTOT * MTOT;
    const int o = n * MTOT + m;
    Cout[o] = vmx + vmn + B[m];
    AM[o]   = (float)imax;
    AN[o]   = (float)imin;
  }
}

extern "C" void kernel_launch(void* const* d_in, const int* in_sizes, int n_in,
                              void* d_out, int out_size, void* d_ws, size_t ws_size,
                              hipStream_t stream) {
  const float* X = (const float*)d_in[0];   // [8,128,512] -> [1024][512]
  const float* W = (const float*)d_in[1];   // [512][512]
  const float* B = (const float*)d_in[2];   // [512]
  float* out = (float*)d_out;

  dim3 grid(MTOT / BM, NTOT / BN);          // (32, 32) = 1024 blocks, 512 thr
  mam_kernel<<<grid, dim3(512), 0, stream>>>(X, W, B, out);
}

// Round 12
// 36.748 us; speedup vs baseline: 3.5983x; 3.5983x over previous
//
#include <hip/hip_runtime.h>
#include <math.h>

// MAM "FullyConnected": C[n,m] = max_k(x[n,k]*w[m,k]) + min_k(...) + bias[m]
// plus argmax/argmin (first occurrence). N=1024, M=512, K=512, f32.
// d_out (read back as f32): C | argmax | argmin, each N*M.
//
// Round 12: R11 spilled (launch_bounds(512,6) -> 85-reg cap -> scratch storm,
// FETCH 173MB). This round: (2 rows x 4 cols)/thread = 3B/product LDS
// (floor 15.4us vs R9's 20.5), live set ~110 regs (w streamed per column),
// launch_bounds(512,4) caps at 128. k-split x4, 4-way LDS merge, recovery
// 2 cells/thread.

constexpr int NTOT = 1024;
constexpr int MTOT = 512;
constexpr int KTOT = 512;
constexpr int BN = 32;
constexpr int BM = 32;
constexpr int BK = 128;
constexpr int G  = 16;        // tournament group size
constexpr int LDSP = 132;     // rows 16B-aligned; distinct rows -> distinct bank groups

__device__ __forceinline__ float max3f(float a, float b, float c) {
  float d; asm("v_max3_f32 %0, %1, %2, %3" : "=v"(d) : "v"(a), "v"(b), "v"(c)); return d;
}
__device__ __forceinline__ float min3f(float a, float b, float c) {
  float d; asm("v_min3_f32 %0, %1, %2, %3" : "=v"(d) : "v"(a), "v"(b), "v"(c)); return d;
}
__device__ __forceinline__ float fmul0(float a, float b) {  // a*b on the 2-cy FMA pipe
  float d; asm("v_fma_f32 %0, %1, %2, 0" : "=v"(d) : "v"(a), "v"(b)); return d;
}
__device__ __forceinline__ float4 f4mul(float4 a, float4 b) {
  return make_float4(fmul0(a.x, b.x), fmul0(a.y, b.y), fmul0(a.z, b.z), fmul0(a.w, b.w));
}

__device__ __forceinline__ void tree16(const float4& q0, const float4& q1,
                                       const float4& q2, const float4& q3,
                                       float& M, float& m) {
  M = fmaxf(max3f(max3f(q0.x, q0.y, q0.z), max3f(q0.w, q1.x, q1.y),
                  max3f(q1.z, q1.w, q2.x)),
            max3f(max3f(q2.y, q2.z, q2.w), q3.x, max3f(q3.y, q3.z, q3.w)));
  m = fminf(min3f(min3f(q0.x, q0.y, q0.z), min3f(q0.w, q1.x, q1.y),
                  min3f(q1.z, q1.w, q2.x)),
            min3f(min3f(q2.y, q2.z, q2.w), q3.x, min3f(q3.y, q3.z, q3.w)));
}

// running update for one cell against one 16-k group's (M,m); strict
// compares keep the FIRST group attaining the extremum.
#define GUPD(S, Mv, mv)                                                      \
  {                                                                          \
    const bool u = (Mv) > vmax##S;                                           \
    vmax##S = u ? (Mv) : vmax##S;  gx##S = u ? gk : gx##S;                   \
    const bool v = (mv) < vmin##S;                                           \
    vmin##S = v ? (mv) : vmin##S;  gn##S = v ? gk : gn##S;                   \
  }

// cell = (x-rows a/b) x (current w column j): 2 cells per call
#define COL_CELLS(Sa, Sb, W0, W1, W2, W3)                                    \
  {                                                                          \
    float M, m;                                                              \
    const float4 qa0 = f4mul(xa0, W0), qa1 = f4mul(xa1, W1);                 \
    const float4 qa2 = f4mul(xa2, W2), qa3 = f4mul(xa3, W3);                 \
    tree16(qa0, qa1, qa2, qa3, M, m);                                        \
    GUPD(Sa, M, m)                                                           \
    const float4 qb0 = f4mul(xb0, W0), qb1 = f4mul(xb1, W1);                 \
    const float4 qb2 = f4mul(xb2, W2), qb3 = f4mul(xb3, W3);                 \
    tree16(qb0, qb1, qb2, qb3, M, m);                                        \
    GUPD(Sb, M, m)                                                           \
  }

// first k in [base, base+16) with x[k]*w[k] == tgt (descending selects ->
// first occurrence wins; +-0 compare-equal so fma(+0) targets match mul).
__device__ __forceinline__ int find_first_eq(const float* __restrict__ xr,
                                             const float* __restrict__ wr,
                                             float tgt, int base) {
  const float4 a0 = *(const float4*)(xr + 0),  a1 = *(const float4*)(xr + 4);
  const float4 a2 = *(const float4*)(xr + 8),  a3 = *(const float4*)(xr + 12);
  const float4 b0 = *(const float4*)(wr + 0),  b1 = *(const float4*)(wr + 4);
  const float4 b2 = *(const float4*)(wr + 8),  b3 = *(const float4*)(wr + 12);
  int idx = base;
  idx = (a3.w * b3.w == tgt) ? base + 15 : idx;
  idx = (a3.z * b3.z == tgt) ? base + 14 : idx;
  idx = (a3.y * b3.y == tgt) ? base + 13 : idx;
  idx = (a3.x * b3.x == tgt) ? base + 12 : idx;
  idx = (a2.w * b2.w == tgt) ? base + 11 : idx;
  idx = (a2.z * b2.z == tgt) ? base + 10 : idx;
  idx = (a2.y * b2.y == tgt) ? base +  9 : idx;
  idx = (a2.x * b2.x == tgt) ? base +  8 : idx;
  idx = (a1.w * b1.w == tgt) ? base +  7 : idx;
  idx = (a1.z * b1.z == tgt) ? base +  6 : idx;
  idx = (a1.y * b1.y == tgt) ? base +  5 : idx;
  idx = (a1.x * b1.x == tgt) ? base +  4 : idx;
  idx = (a0.w * b0.w == tgt) ? base +  3 : idx;
  idx = (a0.z * b0.z == tgt) ? base +  2 : idx;
  idx = (a0.y * b0.y == tgt) ? base +  1 : idx;
  idx = (a0.x * b0.x == tgt) ? base +  0 : idx;
  return idx;
}

__global__ __launch_bounds__(512, 4) void mam_kernel(
    const float* __restrict__ X,   // [NTOT][KTOT]
    const float* __restrict__ W,   // [MTOT][KTOT]
    const float* __restrict__ B,   // [MTOT]
    float* __restrict__ out)
{
  __shared__ float sx[BN][LDSP];   // 16.9 KB
  __shared__ float sw[BM][LDSP];   // 16.9 KB

  const int th      = threadIdx.x;     // 0..511
  const int quarter = th >> 7;         // 0..3 (2 waves each), k-split quarter
  const int t       = th & 127;
  const int n0 = blockIdx.y * BN;
  const int m0 = blockIdx.x * BM;

  const int tn = t >> 3;               // 0..15
  const int tm = t & 7;                // 0..7
  const int r0 = tn, r1 = tn + 16;     // 2 output rows (of 32)
  const int c0 = tm, c1 = tm + 8, c2 = tm + 16, c3 = tm + 24;  // 4 cols
  const int kbase = quarter * 32;      // this quarter's kk range within BK

  // 8 cells: rows {a=r0, b=r1} x cols {0..3}
  float vmaxa0 = -INFINITY, vmaxa1 = -INFINITY, vmaxa2 = -INFINITY, vmaxa3 = -INFINITY;
  float vmaxb0 = -INFINITY, vmaxb1 = -INFINITY, vmaxb2 = -INFINITY, vmaxb3 = -INFINITY;
  float vmina0 =  INFINITY, vmina1 =  INFINITY, vmina2 =  INFINITY, vmina3 =  INFINITY;
  float vminb0 =  INFINITY, vminb1 =  INFINITY, vminb2 =  INFINITY, vminb3 =  INFINITY;
  int gxa0 = 0, gxa1 = 0, gxa2 = 0, gxa3 = 0, gxb0 = 0, gxb1 = 0, gxb2 = 0, gxb3 = 0;
  int gna0 = 0, gna1 = 0, gna2 = 0, gna3 = 0, gnb0 = 0, gnb1 = 0, gnb2 = 0, gnb3 = 0;

  #pragma unroll 1
  for (int kc = 0; kc < KTOT; kc += BK) {
    __syncthreads();  // protect LDS from previous iteration's readers
    // stage x[32][128] + w[32][128]: 1024 float4 each, 512 threads -> 2+2
    #pragma unroll
    for (int j = 0; j < 2; ++j) {
      const int id = th + 512 * j;     // 0..1023
      const int r  = id >> 5;          // 0..31
      const int f  = id & 31;
      *reinterpret_cast<float4*>(&sx[r][f * 4]) =
          *reinterpret_cast<const float4*>(&X[(n0 + r) * KTOT + kc + f * 4]);
      *reinterpret_cast<float4*>(&sw[r][f * 4]) =
          *reinterpret_cast<const float4*>(&W[(m0 + r) * KTOT + kc + f * 4]);
    }
    __syncthreads();

    #pragma unroll
    for (int g = 0; g < 2; ++g) {      // this quarter's 2 groups of 16 k
      const int off = kbase + g * G;   // wave-uniform
      const int gk  = kc + off;
      const float4* xap = reinterpret_cast<const float4*>(&sx[r0][off]);
      const float4* xbp = reinterpret_cast<const float4*>(&sx[r1][off]);
      const float4 xa0 = xap[0], xa1 = xap[1], xa2 = xap[2], xa3 = xap[3];
      const float4 xb0 = xbp[0], xb1 = xbp[1], xb2 = xbp[2], xb3 = xbp[3];

      {
        const float4* wp = reinterpret_cast<const float4*>(&sw[c0][off]);
        const float4 w0 = wp[0], w1 = wp[1], w2 = wp[2], w3 = wp[3];
        COL_CELLS(a0, b0, w0, w1, w2, w3)
      }
      {
        const float4* wp = reinterpret_cast<const float4*>(&sw[c1][off]);
        const float4 w0 = wp[0], w1 = wp[1], w2 = wp[2], w3 = wp[3];
        COL_CELLS(a1, b1, w0, w1, w2, w3)
      }
      {
        const float4* wp = reinterpret_cast<const float4*>(&sw[c2][off]);
        const float4 w0 = wp[0], w1 = wp[1], w2 = wp[2], w3 = wp[3];
        COL_CELLS(a2, b2, w0, w1, w2, w3)
      }
      {
        const float4* wp = reinterpret_cast<const float4*>(&sw[c3][off]);
        const float4 w0 = wp[0], w1 = wp[1], w2 = wp[2], w3 = wp[3];
        COL_CELLS(a3, b3, w0, w1, w2, w3)
      }
    }
  }

  // ---- cross-quarter merge through LDS (ties -> min group id) ----
  // 1024 cells (32x32) * float4 = 16 KB per buffer.
  __syncthreads();
  float* combA = &sx[0][0];
  float* combB = &sw[0][0];

#define WRITE_ONE(S, RR, CC, comb)                                           \
  *reinterpret_cast<float4*>(&(comb)[((RR) * 32 + (CC)) * 4]) =              \
      make_float4(vmax##S, __int_as_float(gx##S), vmin##S, __int_as_float(gn##S));

#define WRITE_PART(comb)                                                     \
  {                                                                          \
    WRITE_ONE(a0, r0, c0, comb) WRITE_ONE(a1, r0, c1, comb)                  \
    WRITE_ONE(a2, r0, c2, comb) WRITE_ONE(a3, r0, c3, comb)                  \
    WRITE_ONE(b0, r1, c0, comb) WRITE_ONE(b1, r1, c1, comb)                  \
    WRITE_ONE(b2, r1, c2, comb) WRITE_ONE(b3, r1, c3, comb)                  \
  }

#define MERGE_ONE(S, RR, CC, comb)                                           \
  {                                                                          \
    const float4 v_ = *reinterpret_cast<const float4*>(&(comb)[((RR) * 32 + (CC)) * 4]); \
    const float pmx = v_.x;  const int pgx = __float_as_int(v_.y);           \
    const float pmn = v_.z;  const int pgn = __float_as_int(v_.w);           \
    if (pmx > vmax##S) { vmax##S = pmx; gx##S = pgx; }                       \
    else if (pmx == vmax##S && pgx < gx##S) { gx##S = pgx; }                 \
    if (pmn < vmin##S) { vmin##S = pmn; gn##S = pgn; }                       \
    else if (pmn == vmin##S && pgn < gn##S) { gn##S = pgn; }                 \
  }

#define MERGE_PART(comb)                                                     \
  {                                                                          \
    MERGE_ONE(a0, r0, c0, comb) MERGE_ONE(a1, r0, c1, comb)                  \
    MERGE_ONE(a2, r0, c2, comb) MERGE_ONE(a3, r0, c3, comb)                  \
    MERGE_ONE(b0, r1, c0, comb) MERGE_ONE(b1, r1, c1, comb)                  \
    MERGE_ONE(b2, r1, c2, comb) MERGE_ONE(b3, r1, c3, comb)                  \
  }

  if (quarter == 1) WRITE_PART(combA);
  if (quarter == 3) WRITE_PART(combB);
  __syncthreads();
  if (quarter == 0) MERGE_PART(combA);
  if (quarter == 2) MERGE_PART(combB);
  __syncthreads();
  if (quarter == 2) WRITE_PART(combA);
  __syncthreads();
  if (quarter == 0) { MERGE_PART(combA); WRITE_PART(combA); }
  __syncthreads();

  // ---- distributed output + windowed index recovery: 2 cells per thread ----
  float* Cout = out;
  float* AM   = out + NTOT * MTOT;
  float* AN   = AM + NTOT * MTOT;

  #pragma unroll
  for (int u = 0; u < 2; ++u) {
    const int cell = th * 2 + u;              // 0..1023 = 32 rows x 32 cols
    const float4 v = *reinterpret_cast<const float4*>(&combA[cell * 4]);
    const float vmx = v.x;  const int gxc = __float_as_int(v.y);
    const float vmn = v.z;  const int gnc = __float_as_int(v.w);
    const int row = cell >> 5, col = cell & 31;
    const int n = n0 + row, m = m0 + col;
    const float* xr = &X[n * KTOT];
    const float* wr = &W[m * KTOT];
    const int imax = find_first_eq(xr + gxc, wr + gxc, vmx, gxc);
    const int imin = find_first_eq(xr + gnc, wr + gnc, vmn, gnc);
    const int o = n * MTOT + m;
    Cout[o] = vmx + vmn + B[m];
    AM[o]   = (float)imax;
    AN[o]   = (float)imin;
  }
}

extern "C" void kernel_launch(void* const* d_in, const int* in_sizes, int n_in,
                              void* d_out, int out_size, void* d_ws, size_t ws_size,
                              hipStream_t stream) {
  const float* X = (const float*)d_in[0];   // [8,128,512] -> [1024][512]
  const float* W = (const float*)d_in[1];   // [512][512]
  const float* B = (const float*)d_in[2];   // [512]
  float* out = (float*)d_out;

  dim3 grid(MTOT / BM, NTOT / BN);          // (16, 32) = 512 blocks, 512 thr
  mam_kernel<<<grid, dim3(512), 0, stream>>>(X, W, B, out);
}

// Round 13
// 34.757 us; speedup vs baseline: 3.8043x; 1.0573x over previous
//
#include <hip/hip_runtime.h>
#include <math.h>

// MAM "FullyConnected": C[n,m] = max_k(x[n,k]*w[m,k]) + min_k(...) + bias[m]
// plus argmax/argmin (first occurrence). N=1024, M=512, K=512, f32.
// d_out (read back as f32): C | argmax | argmin, each N*M.
//
// Round 13: R9 structure (proven 32.6us), but x bypasses LDS: w in LDS
// (8 ds_read_b128/g-iter), x straight from global/L1 (8 dwordx4/g-iter).
// LDS pipe demand halves (20.5 -> 10.2us); x rides the idle TA/L1 pipe.
// Compiler rematerialization of x is now a (cached) global load, dodging
// the R10/R12 LDS re-read failure mode.

constexpr int NTOT = 1024;
constexpr int MTOT = 512;
constexpr int KTOT = 512;
constexpr int BN = 32;
constexpr int BM = 32;
constexpr int BK = 128;
constexpr int G  = 16;        // tournament group size
constexpr int LDSP = 132;     // rows 16B-aligned

__device__ __forceinline__ float max3f(float a, float b, float c) {
  float d; asm("v_max3_f32 %0, %1, %2, %3" : "=v"(d) : "v"(a), "v"(b), "v"(c)); return d;
}
__device__ __forceinline__ float min3f(float a, float b, float c) {
  float d; asm("v_min3_f32 %0, %1, %2, %3" : "=v"(d) : "v"(a), "v"(b), "v"(c)); return d;
}
__device__ __forceinline__ float fmul0(float a, float b) {  // a*b on the 2-cy FMA pipe
  float d; asm("v_fma_f32 %0, %1, %2, 0" : "=v"(d) : "v"(a), "v"(b)); return d;
}
__device__ __forceinline__ float4 f4mul(float4 a, float4 b) {
  return make_float4(fmul0(a.x, b.x), fmul0(a.y, b.y), fmul0(a.z, b.z), fmul0(a.w, b.w));
}

__device__ __forceinline__ void tree16(const float4& q0, const float4& q1,
                                       const float4& q2, const float4& q3,
                                       float& M, float& m) {
  M = fmaxf(max3f(max3f(q0.x, q0.y, q0.z), max3f(q0.w, q1.x, q1.y),
                  max3f(q1.z, q1.w, q2.x)),
            max3f(max3f(q2.y, q2.z, q2.w), q3.x, max3f(q3.y, q3.z, q3.w)));
  m = fminf(min3f(min3f(q0.x, q0.y, q0.z), min3f(q0.w, q1.x, q1.y),
                  min3f(q1.z, q1.w, q2.x)),
            min3f(min3f(q2.y, q2.z, q2.w), q3.x, min3f(q3.y, q3.z, q3.w)));
}

// value tree over one 16-k group for one cell + running group update.
// strict > / < : first group attaining the extremum wins (first occurrence).
#define CELL(S, A0, A1, A2, A3, B0, B1, B2, B3)                              \
  {                                                                          \
    const float4 q0 = f4mul(A0, B0), q1 = f4mul(A1, B1);                     \
    const float4 q2 = f4mul(A2, B2), q3 = f4mul(A3, B3);                     \
    float M, m;                                                              \
    tree16(q0, q1, q2, q3, M, m);                                            \
    const bool u = M > vmax##S;                                              \
    vmax##S = u ? M : vmax##S;  gx##S = u ? gk : gx##S;                      \
    const bool v = m < vmin##S;                                              \
    vmin##S = v ? m : vmin##S;  gn##S = v ? gk : gn##S;                      \
  }

// first k in [base, base+16) with x[k]*w[k] == tgt (descending selects ->
// first occurrence wins; +-0 compare-equal so fma(+0) targets match mul).
__device__ __forceinline__ int find_first_eq(const float* __restrict__ xr,
                                             const float* __restrict__ wr,
                                             float tgt, int base) {
  const float4 a0 = *(const float4*)(xr + 0),  a1 = *(const float4*)(xr + 4);
  const float4 a2 = *(const float4*)(xr + 8),  a3 = *(const float4*)(xr + 12);
  const float4 b0 = *(const float4*)(wr + 0),  b1 = *(const float4*)(wr + 4);
  const float4 b2 = *(const float4*)(wr + 8),  b3 = *(const float4*)(wr + 12);
  int idx = base;
  idx = (a3.w * b3.w == tgt) ? base + 15 : idx;
  idx = (a3.z * b3.z == tgt) ? base + 14 : idx;
  idx = (a3.y * b3.y == tgt) ? base + 13 : idx;
  idx = (a3.x * b3.x == tgt) ? base + 12 : idx;
  idx = (a2.w * b2.w == tgt) ? base + 11 : idx;
  idx = (a2.z * b2.z == tgt) ? base + 10 : idx;
  idx = (a2.y * b2.y == tgt) ? base +  9 : idx;
  idx = (a2.x * b2.x == tgt) ? base +  8 : idx;
  idx = (a1.w * b1.w == tgt) ? base +  7 : idx;
  idx = (a1.z * b1.z == tgt) ? base +  6 : idx;
  idx = (a1.y * b1.y == tgt) ? base +  5 : idx;
  idx = (a1.x * b1.x == tgt) ? base +  4 : idx;
  idx = (a0.w * b0.w == tgt) ? base +  3 : idx;
  idx = (a0.z * b0.z == tgt) ? base +  2 : idx;
  idx = (a0.y * b0.y == tgt) ? base +  1 : idx;
  idx = (a0.x * b0.x == tgt) ? base +  0 : idx;
  return idx;
}

__global__ __launch_bounds__(512, 4) void mam_kernel(
    const float* __restrict__ X,   // [NTOT][KTOT]
    const float* __restrict__ W,   // [MTOT][KTOT]
    const float* __restrict__ B,   // [MTOT]
    float* __restrict__ out)
{
  __shared__ float sw[BM][LDSP];   // 16.9 KB (w tile only; x bypasses LDS)

  const int th   = threadIdx.x;        // 0..511
  const int half = th >> 8;            // 0: kk [0,64), 1: kk [64,128)
  const int t    = th & 255;
  const int n0 = blockIdx.y * BN;
  const int m0 = blockIdx.x * BM;

  const int tn = t >> 4;               // 0..15
  const int tm = t & 15;               // 0..15
  const int r0 = tn, r1 = tn + 16;     // 2 output rows
  const int c0 = tm, c1 = tm + 16;     // 2 output cols
  const int kbase = half * 64;

  const float* Xr0 = &X[(n0 + r0) * KTOT];
  const float* Xr1 = &X[(n0 + r1) * KTOT];

  float vmax00 = -INFINITY, vmax01 = -INFINITY, vmax10 = -INFINITY, vmax11 = -INFINITY;
  float vmin00 =  INFINITY, vmin01 =  INFINITY, vmin10 =  INFINITY, vmin11 =  INFINITY;
  int   gx00 = 0, gx01 = 0, gx10 = 0, gx11 = 0;
  int   gn00 = 0, gn01 = 0, gn10 = 0, gn11 = 0;

  #pragma unroll 1
  for (int kc = 0; kc < KTOT; kc += BK) {
    __syncthreads();  // protect LDS from previous iteration's readers
    // stage w[32][128] only: 1024 float4, 512 threads -> 2 each
    #pragma unroll
    for (int j = 0; j < 2; ++j) {
      const int id = th + 512 * j;     // 0..1023
      const int r  = id >> 5;          // 0..31
      const int f  = id & 31;
      *reinterpret_cast<float4*>(&sw[r][f * 4]) =
          *reinterpret_cast<const float4*>(&W[(m0 + r) * KTOT + kc + f * 4]);
    }
    __syncthreads();

    #pragma unroll
    for (int g = 0; g < 4; ++g) {      // this half's 4 groups of 16 k
      const int off = kbase + g * G;   // wave-uniform
      const int gk  = kc + off;
      // x straight from global (L1/L2-resident, broadcast across 16 threads/row)
      const float4 xa0 = *reinterpret_cast<const float4*>(Xr0 + gk + 0);
      const float4 xa1 = *reinterpret_cast<const float4*>(Xr0 + gk + 4);
      const float4 xa2 = *reinterpret_cast<const float4*>(Xr0 + gk + 8);
      const float4 xa3 = *reinterpret_cast<const float4*>(Xr0 + gk + 12);
      const float4 xb0 = *reinterpret_cast<const float4*>(Xr1 + gk + 0);
      const float4 xb1 = *reinterpret_cast<const float4*>(Xr1 + gk + 4);
      const float4 xb2 = *reinterpret_cast<const float4*>(Xr1 + gk + 8);
      const float4 xb3 = *reinterpret_cast<const float4*>(Xr1 + gk + 12);
      // w from LDS
      const float4* wap = reinterpret_cast<const float4*>(&sw[c0][off]);
      const float4* wbp = reinterpret_cast<const float4*>(&sw[c1][off]);
      const float4 wa0 = wap[0], wa1 = wap[1], wa2 = wap[2], wa3 = wap[3];
      const float4 wb0 = wbp[0], wb1 = wbp[1], wb2 = wbp[2], wb3 = wbp[3];

      CELL(00, xa0, xa1, xa2, xa3, wa0, wa1, wa2, wa3)
      CELL(01, xa0, xa1, xa2, xa3, wb0, wb1, wb2, wb3)
      CELL(10, xb0, xb1, xb2, xb3, wa0, wa1, wa2, wa3)
      CELL(11, xb0, xb1, xb2, xb3, wb0, wb1, wb2, wb3)
    }
  }

  // ---- cross-half combine through LDS (ties -> min group id) ----
  __syncthreads();
  float* comb = &sw[0][0];   // 1024 cells * 4 floats = 16 KB (fits sw)
  if (half == 1) {
    const int cells[4][2] = {{r0, c0}, {r0, c1}, {r1, c0}, {r1, c1}};
    const float vals[4][2] = {{vmax00, vmin00}, {vmax01, vmin01},
                              {vmax10, vmin10}, {vmax11, vmin11}};
    const int gids[4][2] = {{gx00, gn00}, {gx01, gn01}, {gx10, gn10}, {gx11, gn11}};
    #pragma unroll
    for (int i = 0; i < 4; ++i) {
      const int cell = cells[i][0] * 32 + cells[i][1];
      *reinterpret_cast<float4*>(&comb[cell * 4]) =
          make_float4(vals[i][0], __int_as_float(gids[i][0]),
                      vals[i][1], __int_as_float(gids[i][1]));
    }
  }
  __syncthreads();

  if (half == 0) {
#define MERGE(S, RR, CC)                                                     \
    {                                                                        \
      const float4 v_ = *reinterpret_cast<const float4*>(&comb[((RR) * 32 + (CC)) * 4]); \
      const float pmx = v_.x;  const int pgx = __float_as_int(v_.y);         \
      const float pmn = v_.z;  const int pgn = __float_as_int(v_.w);         \
      if (pmx > vmax##S) { vmax##S = pmx; gx##S = pgx; }                     \
      else if (pmx == vmax##S && pgx < gx##S) { gx##S = pgx; }               \
      if (pmn < vmin##S) { vmin##S = pmn; gn##S = pgn; }                     \
      else if (pmn == vmin##S && pgn < gn##S) { gn##S = pgn; }               \
    }
    MERGE(00, r0, c0)
    MERGE(01, r0, c1)
    MERGE(10, r1, c0)
    MERGE(11, r1, c1)

    // windowed index recovery (L2 hits), then outputs
    const float* Wc0 = &W[(m0 + c0) * KTOT];
    const float* Wc1 = &W[(m0 + c1) * KTOT];

    const int imax00 = find_first_eq(Xr0 + gx00, Wc0 + gx00, vmax00, gx00);
    const int imin00 = find_first_eq(Xr0 + gn00, Wc0 + gn00, vmin00, gn00);
    const int imax01 = find_first_eq(Xr0 + gx01, Wc1 + gx01, vmax01, gx01);
    const int imin01 = find_first_eq(Xr0 + gn01, Wc1 + gn01, vmin01, gn01);
    const int imax10 = find_first_eq(Xr1 + gx10, Wc0 + gx10, vmax10, gx10);
    const int imin10 = find_first_eq(Xr1 + gn10, Wc0 + gn10, vmin10, gn10);
    const int imax11 = find_first_eq(Xr1 + gx11, Wc1 + gx11, vmax11, gx11);
    const int imin11 = find_first_eq(Xr1 + gn11, Wc1 + gn11, vmin11, gn11);

    float* Cout = out;
    float* AM   = out + NTOT * MTOT;
    float* AN   = AM + NTOT * MTOT;

    const float b0 = B[m0 + c0];
    const float b1 = B[m0 + c1];

    const int o00 = (n0 + r0) * MTOT + (m0 + c0);
    const int o01 = (n0 + r0) * MTOT + (m0 + c1);
    const int o10 = (n0 + r1) * MTOT + (m0 + c0);
    const int o11 = (n0 + r1) * MTOT + (m0 + c1);

    Cout[o00] = vmax00 + vmin00 + b0;  AM[o00] = (float)imax00;  AN[o00] = (float)imin00;
    Cout[o01] = vmax01 + vmin01 + b1;  AM[o01] = (float)imax01;  AN[o01] = (float)imin01;
    Cout[o10] = vmax10 + vmin10 + b0;  AM[o10] = (float)imax10;  AN[o10] = (float)imin10;
    Cout[o11] = vmax11 + vmin11 + b1;  AM[o11] = (float)imax11;  AN[o11] = (float)imin11;
  }
}

extern "C" void kernel_launch(void* const* d_in, const int* in_sizes, int n_in,
                              void* d_out, int out_size, void* d_ws, size_t ws_size,
                              hipStream_t stream) {
  const float* X = (const float*)d_in[0];   // [8,128,512] -> [1024][512]
  const float* W = (const float*)d_in[1];   // [512][512]
  const float* B = (const float*)d_in[2];   // [512]
  float* out = (float*)d_out;

  dim3 grid(MTOT / BM, NTOT / BN);          // (16, 32) = 512 blocks, 512 thr
  mam_kernel<<<grid, dim3(512), 0, stream>>>(X, W, B, out);
}